// Round 13
// baseline (425.659 us; speedup 1.0000x reference)
//
#include <hip/hip_runtime.h>
#include <math.h>

// Problem constants
#define BATCH  128
#define NIN    1152
#define DIN    8
#define NOUTC  10
#define DOUT   16
#define H1DIM  512
#define H2DIM  1024
#define PIX    784
#define NROWS  (BATCH * NOUTC)   // 1280
#define MROWS  (BATCH * 9)       // 1152 decoder rows (class 9 unused)
#define NBY3   13                // ceil(784/64) col-tiles in gemm3

typedef __attribute__((ext_vector_type(8))) __bf16 bf16x8;
typedef __attribute__((ext_vector_type(4))) float  f32x4;

__device__ __forceinline__ float bf2f(unsigned int u) {
    union { unsigned int i; float f; } v; v.i = u << 16; return v.f;
}
__device__ __forceinline__ ushort f2bf(float f) {
    union { float f; unsigned int i; } v; v.f = f;
    unsigned int r = v.i + 0x7FFFu + ((v.i >> 16) & 1u);
    return (ushort)(r >> 16);
}
__device__ __forceinline__ float ldin(const void* p, size_t i, int isbf) {
    return isbf ? bf2f(((const ushort*)p)[i]) : ((const float*)p)[i];
}
__device__ __forceinline__ bf16x8 frag_of(uint4 u) {
    return __builtin_bit_cast(bf16x8, u);
}
__device__ __forceinline__ bf16x8 ld_frag(const ushort* p) {
    return frag_of(*(const uint4*)p);
}
__device__ __forceinline__ float dot8(uint4 a, uint4 b) {
    float s;
    s  = bf2f(a.x & 0xffffu) * bf2f(b.x & 0xffffu);
    s += bf2f(a.x >> 16)     * bf2f(b.x >> 16);
    s += bf2f(a.y & 0xffffu) * bf2f(b.y & 0xffffu);
    s += bf2f(a.y >> 16)     * bf2f(b.y >> 16);
    s += bf2f(a.z & 0xffffu) * bf2f(b.z & 0xffffu);
    s += bf2f(a.z >> 16)     * bf2f(b.z >> 16);
    s += bf2f(a.w & 0xffffu) * bf2f(b.w & 0xffffu);
    s += bf2f(a.w >> 16)     * bf2f(b.w >> 16);
    return s;
}
__device__ __forceinline__ uint4 pack8(float4 a, float4 b) {
    uint4 r;
    r.x = f2bf(a.x) | ((unsigned)f2bf(a.y) << 16);
    r.y = f2bf(a.z) | ((unsigned)f2bf(a.w) << 16);
    r.z = f2bf(b.x) | ((unsigned)f2bf(b.y) << 16);
    r.w = f2bf(b.z) | ((unsigned)f2bf(b.w) << 16);
    return r;
}
__device__ __forceinline__ int detect_bf(const void* w, int* cntS) {
    int tid = threadIdx.x, nt = blockDim.x;
    if (tid == 0) *cntS = 0;
    __syncthreads();
    const ushort* u = (const ushort*)w;
    int c = 0;
    for (int s = tid; s < 512; s += nt) {
        int e = (u[s * 2] >> 7) & 0xFF;
        if (e >= 88 && e <= 140) c++;
    }
    atomicAdd(cntS, c);
    __syncthreads();
    return (*cntS >= 384) ? 1 : 0;
}

// ---------------------------------------------------------------------------
// prep: dtype flag + small-tensor conversions + weight transposes.
// blockIdx.y: 0:W1 1:b1 2:b2 3:b3 4:x 5:W2^T 6:W3^T.
// ---------------------------------------------------------------------------
struct PrepArgs {
    const void* w;
    const void* src[7];
    ushort*     dst[7];
    int         n[7];
    int*        flag;
};

__global__ __launch_bounds__(256) void prep_kernel(PrepArgs a)
{
    __shared__ int cntS;
    __shared__ ushort tile[32][33];
    int tid = threadIdx.x;
    int isbf = detect_bf(a.w, &cntS);
    int seg = blockIdx.y;
    if (seg == 0 && blockIdx.x == 0 && tid == 0) *a.flag = isbf;

    if (seg <= 4) {
        int n = a.n[seg];
        int stride = gridDim.x * 256;
        ushort* d = a.dst[seg];
        if (isbf) {
            const ushort* s = (const ushort*)a.src[seg];
            for (int i = blockIdx.x * 256 + tid; i < n; i += stride) d[i] = s[i];
        } else {
            const float* s = (const float*)a.src[seg];
            for (int i = blockIdx.x * 256 + tid; i < n; i += stride) d[i] = f2bf(s[i]);
        }
        return;
    }
    int R = (seg == 5) ? H1DIM : H2DIM;
    int C = (seg == 5) ? H2DIM : PIX;
    int tilesX = (seg == 5) ? 32 : 25;
    int tilesY = (seg == 5) ? 16 : 32;
    int t = blockIdx.x;
    if (t >= tilesX * tilesY) return;
    int tx2 = t % tilesX, ty2 = t / tilesX;
    int c0 = tx2 * 32, r0 = ty2 * 32;
    const void* in = a.src[seg];
    ushort* out = a.dst[seg];
    int tx = tid & 31, ty = tid >> 5;
    for (int i = ty; i < 32; i += 8) {
        int r = r0 + i, c = c0 + tx;
        tile[i][tx] = (r < R && c < C) ? f2bf(ldin(in, (size_t)r * C + c, isbf)) : (ushort)0;
    }
    __syncthreads();
    for (int i = ty; i < 32; i += 8) {
        int c = c0 + i, r = r0 + tx;
        if (c < C && r < R) out[(size_t)c * R + r] = tile[tx][i];
    }
}

// ---------------------------------------------------------------------------
// reduce_pass: one 512-thread block per (b,n). hat is COMPUTED into registers
// from L2-resident w (2.95 MB) and inc (2.3 MB) — no hat workspace at all.
// Thread (kb=tid>>1, h=tid&1) owns rows kb+256j (j<4; +row 1024+kb if tid<256).
// Fuses r-scale_coef, rc-weighting (c precomputed in gemm2's shadow),
// weighted k-sum, squash, bscore, decoder layer-1 (compact rows b*9+n).
// ---------------------------------------------------------------------------
__global__ __launch_bounds__(512, 4) void reduce_pass(
    const void*   __restrict__ incRaw,
    const void*   __restrict__ wRaw,
    const ushort* __restrict__ cbuf,       // (B*NOUTC, NIN) precomputed c
    const float*  __restrict__ partials,   // (MROWS, 16)
    int iter0,
    const ushort* __restrict__ W1c,
    const ushort* __restrict__ b1c,
    ushort* __restrict__ h1out,            // (MROWS, 512) (may be null)
    ushort* __restrict__ bsOut,            // (B*NOUTC, NIN) (may be null)
    void*   __restrict__ outFinal,
    const int* __restrict__ flagp)
{
    int bn  = blockIdx.x;
    int n   = bn % NOUTC;
    int b   = bn / NOUTC;
    int tid = threadIdx.x;
    int isbf = *flagp;

    __shared__ ushort wSb[NIN];            // 2.3 KB
    __shared__ float  redS[8][16];
    __shared__ float  sumS[16];
    __shared__ float  ocS[16];
    __shared__ float  scaleS;

    int h = tid & 1, kb = tid >> 1;
    int wave = tid >> 6, lane = tid & 63;
    int nrows = (tid < 256) ? 5 : 4;

    // compute hat rows straight into registers (w/inc are L2-hot)
    uint4 v[5];
    #pragma unroll
    for (int j = 0; j < 5; j++) {
        if (j >= nrows) break;
        int k = kb + 256 * j;               // j==4 -> 1024+kb (kb<128)
        size_t woff = ((size_t)n * NIN + k) * DOUT + (size_t)h * 8; // row-of-8 units
        size_t ioff = ((size_t)b * NIN + k) * DIN;
        uint4 iu;
        unsigned int hh[8];
        if (isbf) {
            iu = *(const uint4*)((const ushort*)incRaw + ioff);
            const uint4* wp = (const uint4*)((const ushort*)wRaw + woff * DIN);
            #pragma unroll
            for (int o = 0; o < 8; o++) hh[o] = f2bf(dot8(wp[o], iu));
        } else {
            const float4* ip = (const float4*)((const float*)incRaw + ioff);
            iu = pack8(ip[0], ip[1]);
            const float4* wp = (const float4*)((const float*)wRaw + woff * DIN);
            #pragma unroll
            for (int o = 0; o < 8; o++) hh[o] = f2bf(dot8(pack8(wp[2 * o], wp[2 * o + 1]), iu));
        }
        v[j].x = hh[0] | (hh[1] << 16);
        v[j].y = hh[2] | (hh[3] << 16);
        v[j].z = hh[4] | (hh[5] << 16);
        v[j].w = hh[6] | (hh[7] << 16);
    }

    // rc weights: r from partials (9 threads), c row coalesced from cbuf
    if (!iter0) {
        if (tid < 9) {
            float s = 0.f;
            #pragma unroll
            for (int j = 0; j < NBY3; j++)
                s += partials[(size_t)(b * 9 + tid) * 16 + j];
            sumS[tid] = -s;
        }
        __syncthreads();
        float mn = 1e30f, mx = -1e30f;
        #pragma unroll
        for (int n2 = 0; n2 < 9; n2++) {
            float vv = sumS[n2];
            mn = fminf(mn, vv); mx = fmaxf(mx, vv);
        }
        float den = fmaxf(mx - mn, 1e-6f);
        float rv = (n < 9) ? fmaxf((sumS[n] - mn) / den, 0.5f) : 0.5f;
        const ushort* crow = cbuf + (size_t)bn * NIN;
        for (int k = tid; k < NIN; k += 512)
            wSb[k] = f2bf(bf2f(crow[k]) * rv);
    }
    __syncthreads();

    // weighted k-sum from registers
    float acc[8];
    #pragma unroll
    for (int o = 0; o < 8; o++) acc[o] = 0.f;
    #pragma unroll
    for (int j = 0; j < 5; j++) {
        if (j >= nrows) break;
        int k = kb + 256 * j;
        float w = iter0 ? 1.f : bf2f(wSb[k]);
        bf16x8 hv = frag_of(v[j]);
        #pragma unroll
        for (int o = 0; o < 8; o++) acc[o] += w * (float)hv[o];
    }
    #pragma unroll
    for (int off = 32; off >= 2; off >>= 1) {
        #pragma unroll
        for (int o = 0; o < 8; o++) acc[o] += __shfl_xor(acc[o], off);
    }
    if (lane < 2) {
        #pragma unroll
        for (int o = 0; o < 8; o++) redS[wave][lane * 8 + o] = acc[o];
    }
    __syncthreads();
    if (tid < 16) {
        float s = 0.f;
        #pragma unroll
        for (int wv = 0; wv < 8; wv++) s += redS[wv][tid];
        sumS[tid] = s;
    }
    __syncthreads();
    if (tid == 0) {
        float n2 = 0.f;
        #pragma unroll
        for (int o = 0; o < 16; o++) n2 += sumS[o] * sumS[o];
        float nrm = sqrtf(n2);
        scaleS = n2 / (1.f + n2) / (nrm + 1e-8f);
    }
    __syncthreads();
    if (tid < 16) {
        float oc = scaleS * sumS[tid];
        ocS[tid] = oc;
        if (outFinal) {
            if (isbf) ((ushort*)outFinal)[(size_t)bn * 16 + tid] = f2bf(oc);
            else      ((float*) outFinal)[(size_t)bn * 16 + tid] = oc;
        }
    }
    __syncthreads();

    // bscore from registers (only classes n<9 feed c)
    if (bsOut && n < 9) {
        float o0 = ocS[h * 8 + 0], o1 = ocS[h * 8 + 1], o2 = ocS[h * 8 + 2],
              o3 = ocS[h * 8 + 3], o4 = ocS[h * 8 + 4], o5 = ocS[h * 8 + 5],
              o6 = ocS[h * 8 + 6], o7 = ocS[h * 8 + 7];
        #pragma unroll
        for (int j = 0; j < 5; j++) {
            if (j >= nrows) break;
            bf16x8 hv = frag_of(v[j]);
            float s = o0 * (float)hv[0] + o1 * (float)hv[1] + o2 * (float)hv[2] +
                      o3 * (float)hv[3] + o4 * (float)hv[4] + o5 * (float)hv[5] +
                      o6 * (float)hv[6] + o7 * (float)hv[7];
            s += __shfl_xor(s, 1);
            if (h == 0) bsOut[(size_t)bn * NIN + kb + 256 * j] = f2bf(s);
        }
    }

    // fused decoder layer 1 (compact rows, classes n<9 only)
    if (h1out && n < 9) {
        int col = tid;
        float acc1 = bf2f(b1c[col]);
        #pragma unroll
        for (int i = 0; i < 16; i++)
            acc1 += ocS[i] * bf2f(W1c[(size_t)(n * 16 + i) * H1DIM + col]);
        h1out[(size_t)(b * 9 + n) * H1DIM + col] = f2bf(fmaxf(acc1, 0.f));
    }
}

// ---------------------------------------------------------------------------
// gemm2: h2 = relu(h1 @ W2T^T + b2), M=1152. grid (18,18): y<16 GEMM tiles,
// y in {16,17}: 36 c-precompute blocks (scale_coef of bscore, coalesced).
// ---------------------------------------------------------------------------
__global__ __launch_bounds__(256) void gemm2_kernel(
    const ushort* __restrict__ A, const ushort* __restrict__ Bt,
    const ushort* __restrict__ bias, ushort* __restrict__ Cout,
    const ushort* __restrict__ bs, ushort* __restrict__ cbuf)
{
    if (blockIdx.y >= 16) {
        int ci = (blockIdx.y - 16) * 18 + blockIdx.x;   // 0..35
        int base = ci * 4096 + threadIdx.x;
        #pragma unroll 4
        for (int j = 0; j < 16; j++) {
            int pi = base + j * 256;                     // 0..147455
            int b = pi / NIN, k = pi - b * NIN;
            const ushort* bp = bs + (size_t)b * NOUTC * NIN + k;
            float vv[9], mn = 1e30f, mx = -1e30f;
            #pragma unroll
            for (int n2 = 0; n2 < 9; n2++) {
                vv[n2] = bf2f(bp[n2 * NIN]);
                mn = fminf(mn, vv[n2]); mx = fmaxf(mx, vv[n2]);
            }
            float den = fmaxf(mx - mn, 1e-6f);
            ushort* cp = cbuf + (size_t)b * NOUTC * NIN + k;
            #pragma unroll
            for (int n2 = 0; n2 < 9; n2++)
                cp[n2 * NIN] = f2bf(fmaxf((vv[n2] - mn) / den, 0.5f));
            cp[9 * NIN] = f2bf(0.5f);
        }
        return;
    }
    int m0 = blockIdx.x * 64, n0 = blockIdx.y * 64;
    int tid = threadIdx.x;
    int wave = tid >> 6, lane = tid & 63, quad = lane >> 4, l16 = lane & 15;

    __shared__ uint4 As4[320];
    __shared__ uint4 Bs4[320];
    ushort* As = (ushort*)As4;
    ushort* Bs = (ushort*)Bs4;

    f32x4 acc[4];
    #pragma unroll
    for (int nt = 0; nt < 4; nt++)
        #pragma unroll
        for (int rg = 0; rg < 4; rg++) acc[nt][rg] = 0.f;

    int sMi = tid >> 2, sKk = (tid & 3) * 8;
    int sLds = sMi * 5 + (tid & 3);
    const ushort* Ap = A + (size_t)(m0 + sMi) * H1DIM + sKk;
    const ushort* Bp = Bt + (size_t)(n0 + sMi) * H1DIM + sKk;

    uint4 aR = *(const uint4*)Ap;
    uint4 bR = *(const uint4*)Bp;

    for (int k0 = 0; k0 < H1DIM; k0 += 32) {
        As4[sLds] = aR;
        Bs4[sLds] = bR;
        __syncthreads();
        if (k0 + 32 < H1DIM) {
            aR = *(const uint4*)(Ap + k0 + 32);
            bR = *(const uint4*)(Bp + k0 + 32);
        }
        bf16x8 a = ld_frag(As + (wave * 16 + l16) * 40 + quad * 8);
        #pragma unroll
        for (int nt = 0; nt < 4; nt++) {
            bf16x8 bb = ld_frag(Bs + (nt * 16 + l16) * 40 + quad * 8);
            acc[nt] = __builtin_amdgcn_mfma_f32_16x16x32_bf16(a, bb, acc[nt], 0, 0, 0);
        }
        __syncthreads();
    }

    int rowBase = m0 + wave * 16 + quad * 4;
    #pragma unroll
    for (int nt = 0; nt < 4; nt++) {
        int col = n0 + nt * 16 + l16;
        float bv = bf2f(bias[col]);
        #pragma unroll
        for (int rg = 0; rg < 4; rg++) {
            float v = acc[nt][rg] + bv;
            Cout[(size_t)(rowBase + rg) * H2DIM + col] = f2bf(fmaxf(v, 0.f));
        }
    }
}

// ---------------------------------------------------------------------------
// gemm3: sigmoid(h2 @ W3T^T + b3) -> squared error vs x -> partials.
// M=1152 compact rows (b = row/9). grid (18, 13).
// ---------------------------------------------------------------------------
__global__ __launch_bounds__(256) void gemm3_kernel(
    const ushort* __restrict__ A, const ushort* __restrict__ Bt,
    const ushort* __restrict__ bias,
    const ushort* __restrict__ xin, float* __restrict__ partials)
{
    int m0 = blockIdx.x * 64, n0 = blockIdx.y * 64;
    int tid = threadIdx.x;
    int wave = tid >> 6, lane = tid & 63, quad = lane >> 4, l16 = lane & 15;

    __shared__ uint4 As4[320];
    __shared__ uint4 Bs4[320];
    ushort* As = (ushort*)As4;
    ushort* Bs = (ushort*)Bs4;

    f32x4 acc[4];
    #pragma unroll
    for (int nt = 0; nt < 4; nt++)
        #pragma unroll
        for (int rg = 0; rg < 4; rg++) acc[nt][rg] = 0.f;

    int sMi = tid >> 2, sKk = (tid & 3) * 8;
    int sLds = sMi * 5 + (tid & 3);
    const ushort* Ap = A + (size_t)(m0 + sMi) * H2DIM + sKk;
    const ushort* Bp = Bt + (size_t)(n0 + sMi) * H2DIM + sKk;
    bool bOK = (n0 + sMi) < PIX;

    uint4 aR = *(const uint4*)Ap;
    uint4 bR = bOK ? *(const uint4*)Bp : make_uint4(0, 0, 0, 0);

    for (int k0 = 0; k0 < H2DIM; k0 += 32) {
        As4[sLds] = aR;
        Bs4[sLds] = bR;
        __syncthreads();
        if (k0 + 32 < H2DIM) {
            aR = *(const uint4*)(Ap + k0 + 32);
            bR = bOK ? *(const uint4*)(Bp + k0 + 32) : make_uint4(0, 0, 0, 0);
        }
        bf16x8 a = ld_frag(As + (wave * 16 + l16) * 40 + quad * 8);
        #pragma unroll
        for (int nt = 0; nt < 4; nt++) {
            bf16x8 bb = ld_frag(Bs + (nt * 16 + l16) * 40 + quad * 8);
            acc[nt] = __builtin_amdgcn_mfma_f32_16x16x32_bf16(a, bb, acc[nt], 0, 0, 0);
        }
        __syncthreads();
    }

    int rowBase = m0 + wave * 16 + quad * 4;
    float vr[4] = {0.f, 0.f, 0.f, 0.f};
    #pragma unroll
    for (int nt = 0; nt < 4; nt++) {
        int col = n0 + nt * 16 + l16;
        if (col < PIX) {
            float bv = bf2f(bias[col]);
            #pragma unroll
            for (int rg = 0; rg < 4; rg++) {
                int row = rowBase + rg;
                int bb = row / 9;
                float z = acc[nt][rg] + bv;
                float s = 1.f / (1.f + __expf(-z));
                float d = bf2f(xin[(size_t)bb * PIX + col]) - s;
                vr[rg] += d * d;
            }
        }
    }
    #pragma unroll
    for (int rg = 0; rg < 4; rg++) {
        float v = vr[rg];
        #pragma unroll
        for (int off = 8; off >= 1; off >>= 1) v += __shfl_xor(v, off, 16);
        if (l16 == 0)
            partials[(size_t)(rowBase + rg) * 16 + blockIdx.y] = v;
    }
}

// ---------------------------------------------------------------------------
extern "C" void kernel_launch(void* const* d_in, const int* in_sizes, int n_in,
                              void* d_out, int out_size, void* d_ws, size_t ws_size,
                              hipStream_t stream)
{
    const void* inc = d_in[0];
    const void* x   = d_in[1];
    const void* w   = d_in[2];
    const void* W1  = d_in[3];
    const void* b1  = d_in[4];
    const void* W2  = d_in[5];
    const void* b2  = d_in[6];
    const void* W3  = d_in[7];
    const void* b3  = d_in[8];

    char* p = (char*)d_ws;
    auto alloc = [&](size_t bytes) { void* r = p; p += (bytes + 255) & ~(size_t)255; return r; };
    int*    flagWS    = (int*)alloc(256);
    ushort* bs        = (ushort*)alloc((size_t)NROWS * NIN * 2);
    ushort* cbuf      = (ushort*)alloc((size_t)NROWS * NIN * 2);
    float*  partials  = (float*)alloc((size_t)MROWS * 16 * 4);
    ushort* h1WS      = (ushort*)alloc((size_t)MROWS * H1DIM * 2);
    ushort* h2WS      = (ushort*)alloc((size_t)MROWS * H2DIM * 2);
    ushort* W2T       = (ushort*)alloc((size_t)H2DIM * H1DIM * 2);
    ushort* W3T       = (ushort*)alloc((size_t)PIX * H2DIM * 2);
    ushort* W1c       = (ushort*)alloc((size_t)160 * H1DIM * 2);
    ushort* b1c       = (ushort*)alloc((size_t)H1DIM * 2);
    ushort* b2c       = (ushort*)alloc((size_t)H2DIM * 2);
    ushort* b3c       = (ushort*)alloc((size_t)PIX * 2);
    ushort* xc        = (ushort*)alloc((size_t)BATCH * PIX * 2);

    PrepArgs pa;
    pa.w = w;
    pa.src[0] = W1;  pa.dst[0] = W1c;  pa.n[0] = 160 * H1DIM;
    pa.src[1] = b1;  pa.dst[1] = b1c;  pa.n[1] = H1DIM;
    pa.src[2] = b2;  pa.dst[2] = b2c;  pa.n[2] = H2DIM;
    pa.src[3] = b3;  pa.dst[3] = b3c;  pa.n[3] = PIX;
    pa.src[4] = x;   pa.dst[4] = xc;   pa.n[4] = BATCH * PIX;
    pa.src[5] = W2;  pa.dst[5] = W2T;  pa.n[5] = 0;
    pa.src[6] = W3;  pa.dst[6] = W3T;  pa.n[6] = 0;
    pa.flag = flagWS;
    prep_kernel<<<dim3(800, 7), 256, 0, stream>>>(pa);

    // iter 0: rc = 1; writes bscore->bs and fused layer-1 h1
    reduce_pass<<<NROWS, 512, 0, stream>>>(
        inc, w, nullptr, nullptr, 1,
        W1c, b1c, h1WS, bs, nullptr, flagWS);

    for (int it = 0; it < 2; it++) {
        gemm2_kernel<<<dim3(18, 18), 256, 0, stream>>>(
            h1WS, W2T, b2c, h2WS, bs, cbuf);
        gemm3_kernel<<<dim3(18, NBY3), 256, 0, stream>>>(
            h2WS, W3T, b3c, xc, partials);

        int last = (it == 1);
        ushort* bsO = last ? nullptr : bs;
        ushort* h1o = last ? nullptr : h1WS;
        void*   fin = last ? d_out : nullptr;
        reduce_pass<<<NROWS, 512, 0, stream>>>(
            inc, w, cbuf, partials, 0,
            W1c, b1c, h1o, bsO, fin, flagWS);
    }
}

// Round 14
// 215.606 us; speedup vs baseline: 1.9742x; 1.9742x over previous
//
#include <hip/hip_runtime.h>
#include <math.h>

// Problem constants
#define BATCH  128
#define NIN    1152
#define DIN    8
#define NOUTC  10
#define DOUT   16
#define H1DIM  512
#define H2DIM  1024
#define PIX    784
#define NROWS  (BATCH * NOUTC)   // 1280
#define MROWS  (BATCH * 9)       // 1152 decoder rows (class 9 unused)
#define NBY3   13                // ceil(784/64) col-tiles in gemm3

typedef __attribute__((ext_vector_type(8))) __bf16 bf16x8;
typedef __attribute__((ext_vector_type(4))) float  f32x4;
typedef __attribute__((ext_vector_type(4))) unsigned int u32x4;

__device__ __forceinline__ float bf2f(unsigned int u) {
    union { unsigned int i; float f; } v; v.i = u << 16; return v.f;
}
__device__ __forceinline__ ushort f2bf(float f) {
    union { float f; unsigned int i; } v; v.f = f;
    unsigned int r = v.i + 0x7FFFu + ((v.i >> 16) & 1u);
    return (ushort)(r >> 16);
}
__device__ __forceinline__ float ldin(const void* p, size_t i, int isbf) {
    return isbf ? bf2f(((const ushort*)p)[i]) : ((const float*)p)[i];
}
__device__ __forceinline__ bf16x8 frag_of(uint4 u) {
    return __builtin_bit_cast(bf16x8, u);
}
__device__ __forceinline__ bf16x8 ld_frag(const ushort* p) {
    return frag_of(*(const uint4*)p);
}
__device__ __forceinline__ float dot8(uint4 a, uint4 b) {
    float s;
    s  = bf2f(a.x & 0xffffu) * bf2f(b.x & 0xffffu);
    s += bf2f(a.x >> 16)     * bf2f(b.x >> 16);
    s += bf2f(a.y & 0xffffu) * bf2f(b.y & 0xffffu);
    s += bf2f(a.y >> 16)     * bf2f(b.y >> 16);
    s += bf2f(a.z & 0xffffu) * bf2f(b.z & 0xffffu);
    s += bf2f(a.z >> 16)     * bf2f(b.z >> 16);
    s += bf2f(a.w & 0xffffu) * bf2f(b.w & 0xffffu);
    s += bf2f(a.w >> 16)     * bf2f(b.w >> 16);
    return s;
}
__device__ __forceinline__ uint4 pack8(float4 a, float4 b) {
    uint4 r;
    r.x = f2bf(a.x) | ((unsigned)f2bf(a.y) << 16);
    r.y = f2bf(a.z) | ((unsigned)f2bf(a.w) << 16);
    r.z = f2bf(b.x) | ((unsigned)f2bf(b.y) << 16);
    r.w = f2bf(b.z) | ((unsigned)f2bf(b.w) << 16);
    return r;
}
__device__ __forceinline__ int detect_bf(const void* w, int* cntS) {
    int tid = threadIdx.x, nt = blockDim.x;
    if (tid == 0) *cntS = 0;
    __syncthreads();
    const ushort* u = (const ushort*)w;
    int c = 0;
    for (int s = tid; s < 512; s += nt) {
        int e = (u[s * 2] >> 7) & 0xFF;
        if (e >= 88 && e <= 140) c++;
    }
    atomicAdd(cntS, c);
    __syncthreads();
    return (*cntS >= 384) ? 1 : 0;
}

// ---------------------------------------------------------------------------
// prep: dtype flag + small-tensor conversions + weight transposes.
// blockIdx.y: 0:W1 1:b1 2:b2 3:b3 4:x 5:W2^T 6:W3^T.
// ---------------------------------------------------------------------------
struct PrepArgs {
    const void* w;
    const void* src[7];
    ushort*     dst[7];
    int         n[7];
    int*        flag;
};

__global__ __launch_bounds__(256) void prep_kernel(PrepArgs a)
{
    __shared__ int cntS;
    __shared__ ushort tile[32][33];
    int tid = threadIdx.x;
    int isbf = detect_bf(a.w, &cntS);
    int seg = blockIdx.y;
    if (seg == 0 && blockIdx.x == 0 && tid == 0) *a.flag = isbf;

    if (seg <= 4) {
        int n = a.n[seg];
        int stride = gridDim.x * 256;
        ushort* d = a.dst[seg];
        if (isbf) {
            const ushort* s = (const ushort*)a.src[seg];
            for (int i = blockIdx.x * 256 + tid; i < n; i += stride) d[i] = s[i];
        } else {
            const float* s = (const float*)a.src[seg];
            for (int i = blockIdx.x * 256 + tid; i < n; i += stride) d[i] = f2bf(s[i]);
        }
        return;
    }
    int R = (seg == 5) ? H1DIM : H2DIM;
    int C = (seg == 5) ? H2DIM : PIX;
    int tilesX = (seg == 5) ? 32 : 25;
    int tilesY = (seg == 5) ? 16 : 32;
    int t = blockIdx.x;
    if (t >= tilesX * tilesY) return;
    int tx2 = t % tilesX, ty2 = t / tilesX;
    int c0 = tx2 * 32, r0 = ty2 * 32;
    const void* in = a.src[seg];
    ushort* out = a.dst[seg];
    int tx = tid & 31, ty = tid >> 5;
    for (int i = ty; i < 32; i += 8) {
        int r = r0 + i, c = c0 + tx;
        tile[i][tx] = (r < R && c < C) ? f2bf(ldin(in, (size_t)r * C + c, isbf)) : (ushort)0;
    }
    __syncthreads();
    for (int i = ty; i < 32; i += 8) {
        int c = c0 + i, r = r0 + tx;
        if (c < C && r < R) out[(size_t)c * R + r] = tile[tx][i];
    }
}

// ---------------------------------------------------------------------------
// hat_build: hat[b,n,k,o] = <W[n,k,o,:], inc[b,k,:]> from RAW w/inc.
// 8 W rows in VGPRs, 16 batches per block. Non-temporal stores stream hat.
// grid (9 kc, 8 bc, 10 n).
// ---------------------------------------------------------------------------
__global__ __launch_bounds__(256) void hat_build(
    const void* __restrict__ inc,
    const void* __restrict__ w,
    ushort* __restrict__ hatG,
    const int* __restrict__ flagp)
{
    int isbf = *flagp;
    int kc = blockIdx.x, bc = blockIdx.y, n = blockIdx.z;
    int t  = threadIdx.x;
    int k  = kc * 128 + (t >> 1);
    int oh = (t & 1) << 3;

    size_t wbase = ((size_t)n * NIN + k) * DOUT + oh;   // row-of-8 units
    uint4 wr[8];
    if (isbf) {
        const uint4* wp = (const uint4*)((const ushort*)w + wbase * DIN);
        #pragma unroll
        for (int j = 0; j < 8; j++) wr[j] = wp[j];
    } else {
        const float4* wp = (const float4*)((const float*)w + wbase * DIN);
        #pragma unroll
        for (int j = 0; j < 8; j++) wr[j] = pack8(wp[2 * j], wp[2 * j + 1]);
    }

    int b0 = bc * 16;
    #pragma unroll 4
    for (int bl = 0; bl < 16; bl++) {
        int b = b0 + bl;
        size_t ioff = ((size_t)b * NIN + k) * DIN;
        uint4 iu;
        if (isbf) iu = *(const uint4*)((const ushort*)inc + ioff);
        else {
            const float4* ip = (const float4*)((const float*)inc + ioff);
            iu = pack8(ip[0], ip[1]);
        }
        unsigned int h[8];
        #pragma unroll
        for (int j = 0; j < 8; j++) h[j] = f2bf(dot8(wr[j], iu));
        u32x4 ov = { h[0] | (h[1] << 16), h[2] | (h[3] << 16),
                     h[4] | (h[5] << 16), h[6] | (h[7] << 16) };
        __builtin_nontemporal_store(ov,
            (u32x4*)(hatG + (((size_t)(b * NOUTC + n) * NIN + k) * DOUT + oh)));
    }
}

// ---------------------------------------------------------------------------
// reduce_pass: one 512-thread block per (b,n). hat loaded from hatG into
// registers (rows kb+256j, parity half h) + 4 KB LDS tail for rows 1024+.
// Fuses r-scale_coef, rc-weighting (c precomputed in gemm2's shadow),
// weighted k-sum, squash, bscore, decoder layer-1 (compact rows b*9+n).
// ---------------------------------------------------------------------------
template<bool COMPUTE>
__global__ __launch_bounds__(512, 4) void reduce_pass(
    const ushort* __restrict__ hatG,
    const void*   __restrict__ incRaw,
    const void*   __restrict__ wRaw,
    const ushort* __restrict__ cbuf,       // (B*NOUTC, NIN) precomputed c
    const float*  __restrict__ partials,   // (MROWS, 16)
    int iter0,
    const ushort* __restrict__ W1c,
    const ushort* __restrict__ b1c,
    ushort* __restrict__ h1out,            // (MROWS, 512) (may be null)
    ushort* __restrict__ bsOut,            // (B*NOUTC, NIN) (may be null)
    void*   __restrict__ outFinal,
    const int* __restrict__ flagp)
{
    int bn  = blockIdx.x;
    int n   = bn % NOUTC;
    int b   = bn / NOUTC;
    int tid = threadIdx.x;

    __shared__ ushort wSb[NIN];
    __shared__ float  redS[8][16];
    __shared__ float  sumS[16];
    __shared__ float  ocS[16];
    __shared__ float  scaleS;

    int h = tid & 1, kb = tid >> 1;
    int wave = tid >> 6, lane = tid & 63;

    uint4 v[4];
    const ushort* tailS;

    if constexpr (!COMPUTE) {
        __shared__ uint4 hatTail4[256];
        const ushort* hbase = hatG + (size_t)bn * NIN * DOUT;
        #pragma unroll
        for (int j = 0; j < 4; j++)
            v[j] = *(const uint4*)(hbase + ((kb + 256 * j) * DOUT + h * 8));
        if (tid < 256)
            hatTail4[tid] = *(const uint4*)(hbase + 1024 * DOUT + tid * 8);
        tailS = (const ushort*)hatTail4;
    } else {
        __shared__ int cntS;
        __shared__ uint4 hatS4[NIN * DOUT / 8];
        int isbf = detect_bf(wRaw, &cntS);
        size_t wnb = (size_t)n * NIN * DOUT * DIN;
        for (int idx = tid; idx < NIN * DOUT; idx += 512) {
            int k = idx >> 4;
            float s = 0.f;
            #pragma unroll
            for (int i = 0; i < 8; i++)
                s += ldin(wRaw, wnb + (size_t)idx * 8 + i, isbf) *
                     ldin(incRaw, ((size_t)b * NIN + k) * DIN + i, isbf);
            ((ushort*)hatS4)[idx] = f2bf(s);
        }
        __syncthreads();
        const ushort* hbase = (const ushort*)hatS4;
        #pragma unroll
        for (int j = 0; j < 4; j++)
            v[j] = *(const uint4*)(hbase + ((kb + 256 * j) * DOUT + h * 8));
        tailS = hbase + 1024 * DOUT;
    }

    // rc weights: r from partials (9 threads), c row coalesced from cbuf
    if (!iter0) {
        if (tid < 9) {
            float s = 0.f;
            #pragma unroll
            for (int j = 0; j < NBY3; j++)
                s += partials[(size_t)(b * 9 + tid) * 16 + j];
            sumS[tid] = -s;
        }
        __syncthreads();
        float mn = 1e30f, mx = -1e30f;
        #pragma unroll
        for (int n2 = 0; n2 < 9; n2++) {
            float vv = sumS[n2];
            mn = fminf(mn, vv); mx = fmaxf(mx, vv);
        }
        float den = fmaxf(mx - mn, 1e-6f);
        float rv = (n < 9) ? fmaxf((sumS[n] - mn) / den, 0.5f) : 0.5f;
        const ushort* crow = cbuf + (size_t)bn * NIN;
        for (int k = tid; k < NIN; k += 512)
            wSb[k] = f2bf(bf2f(crow[k]) * rv);
    }
    __syncthreads();

    // weighted k-sum from registers (+ LDS tail)
    float acc[8];
    #pragma unroll
    for (int o = 0; o < 8; o++) acc[o] = 0.f;
    #pragma unroll
    for (int j = 0; j < 4; j++) {
        int k = kb + 256 * j;
        float w = iter0 ? 1.f : bf2f(wSb[k]);
        bf16x8 hv = frag_of(v[j]);
        #pragma unroll
        for (int o = 0; o < 8; o++) acc[o] += w * (float)hv[o];
    }
    if (tid < 256) {
        int k = 1024 + kb;
        float w = iter0 ? 1.f : bf2f(wSb[k]);
        bf16x8 hv = ld_frag(tailS + kb * DOUT + h * 8);
        #pragma unroll
        for (int o = 0; o < 8; o++) acc[o] += w * (float)hv[o];
    }
    #pragma unroll
    for (int off = 32; off >= 2; off >>= 1) {
        #pragma unroll
        for (int o = 0; o < 8; o++) acc[o] += __shfl_xor(acc[o], off);
    }
    if (lane < 2) {
        #pragma unroll
        for (int o = 0; o < 8; o++) redS[wave][lane * 8 + o] = acc[o];
    }
    __syncthreads();
    if (tid < 16) {
        float s = 0.f;
        #pragma unroll
        for (int wv = 0; wv < 8; wv++) s += redS[wv][tid];
        sumS[tid] = s;
    }
    __syncthreads();
    if (tid == 0) {
        float n2 = 0.f;
        #pragma unroll
        for (int o = 0; o < 16; o++) n2 += sumS[o] * sumS[o];
        float nrm = sqrtf(n2);
        scaleS = n2 / (1.f + n2) / (nrm + 1e-8f);
    }
    __syncthreads();
    if (tid < 16) {
        float oc = scaleS * sumS[tid];
        ocS[tid] = oc;
        if (outFinal) {
            if (*flagp) ((ushort*)outFinal)[(size_t)bn * 16 + tid] = f2bf(oc);
            else        ((float*) outFinal)[(size_t)bn * 16 + tid] = oc;
        }
    }
    __syncthreads();

    // bscore (only classes n<9 feed c)
    if (bsOut && n < 9) {
        float o0 = ocS[h * 8 + 0], o1 = ocS[h * 8 + 1], o2 = ocS[h * 8 + 2],
              o3 = ocS[h * 8 + 3], o4 = ocS[h * 8 + 4], o5 = ocS[h * 8 + 5],
              o6 = ocS[h * 8 + 6], o7 = ocS[h * 8 + 7];
        #pragma unroll
        for (int j = 0; j < 4; j++) {
            bf16x8 hv = frag_of(v[j]);
            float s = o0 * (float)hv[0] + o1 * (float)hv[1] + o2 * (float)hv[2] +
                      o3 * (float)hv[3] + o4 * (float)hv[4] + o5 * (float)hv[5] +
                      o6 * (float)hv[6] + o7 * (float)hv[7];
            s += __shfl_xor(s, 1);
            if (h == 0) bsOut[(size_t)bn * NIN + kb + 256 * j] = f2bf(s);
        }
        if (tid < 256) {
            bf16x8 hv = ld_frag(tailS + kb * DOUT + h * 8);
            float s = o0 * (float)hv[0] + o1 * (float)hv[1] + o2 * (float)hv[2] +
                      o3 * (float)hv[3] + o4 * (float)hv[4] + o5 * (float)hv[5] +
                      o6 * (float)hv[6] + o7 * (float)hv[7];
            s += __shfl_xor(s, 1);
            if (h == 0) bsOut[(size_t)bn * NIN + 1024 + kb] = f2bf(s);
        }
    }

    // fused decoder layer 1 (compact rows, classes n<9 only)
    if (h1out && n < 9) {
        int col = tid;
        float acc1 = bf2f(b1c[col]);
        #pragma unroll
        for (int i = 0; i < 16; i++)
            acc1 += ocS[i] * bf2f(W1c[(size_t)(n * 16 + i) * H1DIM + col]);
        h1out[(size_t)(b * 9 + n) * H1DIM + col] = f2bf(fmaxf(acc1, 0.f));
    }
}

// ---------------------------------------------------------------------------
// gemm2: h2 = relu(h1 @ W2T^T + b2), M=1152. grid (18,18): y<16 GEMM tiles,
// y in {16,17}: 36 c-precompute blocks (scale_coef of bscore, coalesced).
// ---------------------------------------------------------------------------
__global__ __launch_bounds__(256) void gemm2_kernel(
    const ushort* __restrict__ A, const ushort* __restrict__ Bt,
    const ushort* __restrict__ bias, ushort* __restrict__ Cout,
    const ushort* __restrict__ bs, ushort* __restrict__ cbuf)
{
    if (blockIdx.y >= 16) {
        int ci = (blockIdx.y - 16) * 18 + blockIdx.x;   // 0..35
        int base = ci * 4096 + threadIdx.x;
        #pragma unroll 4
        for (int j = 0; j < 16; j++) {
            int pi = base + j * 256;                     // 0..147455
            int b = pi / NIN, k = pi - b * NIN;
            const ushort* bp = bs + (size_t)b * NOUTC * NIN + k;
            float vv[9], mn = 1e30f, mx = -1e30f;
            #pragma unroll
            for (int n2 = 0; n2 < 9; n2++) {
                vv[n2] = bf2f(bp[n2 * NIN]);
                mn = fminf(mn, vv[n2]); mx = fmaxf(mx, vv[n2]);
            }
            float den = fmaxf(mx - mn, 1e-6f);
            ushort* cp = cbuf + (size_t)b * NOUTC * NIN + k;
            #pragma unroll
            for (int n2 = 0; n2 < 9; n2++)
                cp[n2 * NIN] = f2bf(fmaxf((vv[n2] - mn) / den, 0.5f));
            cp[9 * NIN] = f2bf(0.5f);
        }
        return;
    }
    int m0 = blockIdx.x * 64, n0 = blockIdx.y * 64;
    int tid = threadIdx.x;
    int wave = tid >> 6, lane = tid & 63, quad = lane >> 4, l16 = lane & 15;

    __shared__ uint4 As4[320];
    __shared__ uint4 Bs4[320];
    ushort* As = (ushort*)As4;
    ushort* Bs = (ushort*)Bs4;

    f32x4 acc[4];
    #pragma unroll
    for (int nt = 0; nt < 4; nt++)
        #pragma unroll
        for (int rg = 0; rg < 4; rg++) acc[nt][rg] = 0.f;

    int sMi = tid >> 2, sKk = (tid & 3) * 8;
    int sLds = sMi * 5 + (tid & 3);
    const ushort* Ap = A + (size_t)(m0 + sMi) * H1DIM + sKk;
    const ushort* Bp = Bt + (size_t)(n0 + sMi) * H1DIM + sKk;

    uint4 aR = *(const uint4*)Ap;
    uint4 bR = *(const uint4*)Bp;

    for (int k0 = 0; k0 < H1DIM; k0 += 32) {
        As4[sLds] = aR;
        Bs4[sLds] = bR;
        __syncthreads();
        if (k0 + 32 < H1DIM) {
            aR = *(const uint4*)(Ap + k0 + 32);
            bR = *(const uint4*)(Bp + k0 + 32);
        }
        bf16x8 a = ld_frag(As + (wave * 16 + l16) * 40 + quad * 8);
        #pragma unroll
        for (int nt = 0; nt < 4; nt++) {
            bf16x8 bb = ld_frag(Bs + (nt * 16 + l16) * 40 + quad * 8);
            acc[nt] = __builtin_amdgcn_mfma_f32_16x16x32_bf16(a, bb, acc[nt], 0, 0, 0);
        }
        __syncthreads();
    }

    int rowBase = m0 + wave * 16 + quad * 4;
    #pragma unroll
    for (int nt = 0; nt < 4; nt++) {
        int col = n0 + nt * 16 + l16;
        float bv = bf2f(bias[col]);
        #pragma unroll
        for (int rg = 0; rg < 4; rg++) {
            float v = acc[nt][rg] + bv;
            Cout[(size_t)(rowBase + rg) * H2DIM + col] = f2bf(fmaxf(v, 0.f));
        }
    }
}

// ---------------------------------------------------------------------------
// gemm3: sigmoid(h2 @ W3T^T + b3) -> squared error vs x -> partials.
// M=1152 compact rows (b = row/9). grid (18, 13).
// ---------------------------------------------------------------------------
__global__ __launch_bounds__(256) void gemm3_kernel(
    const ushort* __restrict__ A, const ushort* __restrict__ Bt,
    const ushort* __restrict__ bias,
    const ushort* __restrict__ xin, float* __restrict__ partials)
{
    int m0 = blockIdx.x * 64, n0 = blockIdx.y * 64;
    int tid = threadIdx.x;
    int wave = tid >> 6, lane = tid & 63, quad = lane >> 4, l16 = lane & 15;

    __shared__ uint4 As4[320];
    __shared__ uint4 Bs4[320];
    ushort* As = (ushort*)As4;
    ushort* Bs = (ushort*)Bs4;

    f32x4 acc[4];
    #pragma unroll
    for (int nt = 0; nt < 4; nt++)
        #pragma unroll
        for (int rg = 0; rg < 4; rg++) acc[nt][rg] = 0.f;

    int sMi = tid >> 2, sKk = (tid & 3) * 8;
    int sLds = sMi * 5 + (tid & 3);
    const ushort* Ap = A + (size_t)(m0 + sMi) * H2DIM + sKk;
    const ushort* Bp = Bt + (size_t)(n0 + sMi) * H2DIM + sKk;
    bool bOK = (n0 + sMi) < PIX;

    uint4 aR = *(const uint4*)Ap;
    uint4 bR = bOK ? *(const uint4*)Bp : make_uint4(0, 0, 0, 0);

    for (int k0 = 0; k0 < H2DIM; k0 += 32) {
        As4[sLds] = aR;
        Bs4[sLds] = bR;
        __syncthreads();
        if (k0 + 32 < H2DIM) {
            aR = *(const uint4*)(Ap + k0 + 32);
            bR = bOK ? *(const uint4*)(Bp + k0 + 32) : make_uint4(0, 0, 0, 0);
        }
        bf16x8 a = ld_frag(As + (wave * 16 + l16) * 40 + quad * 8);
        #pragma unroll
        for (int nt = 0; nt < 4; nt++) {
            bf16x8 bb = ld_frag(Bs + (nt * 16 + l16) * 40 + quad * 8);
            acc[nt] = __builtin_amdgcn_mfma_f32_16x16x32_bf16(a, bb, acc[nt], 0, 0, 0);
        }
        __syncthreads();
    }

    int rowBase = m0 + wave * 16 + quad * 4;
    float vr[4] = {0.f, 0.f, 0.f, 0.f};
    #pragma unroll
    for (int nt = 0; nt < 4; nt++) {
        int col = n0 + nt * 16 + l16;
        if (col < PIX) {
            float bv = bf2f(bias[col]);
            #pragma unroll
            for (int rg = 0; rg < 4; rg++) {
                int row = rowBase + rg;
                int bb = row / 9;
                float z = acc[nt][rg] + bv;
                float s = 1.f / (1.f + __expf(-z));
                float d = bf2f(xin[(size_t)bb * PIX + col]) - s;
                vr[rg] += d * d;
            }
        }
    }
    #pragma unroll
    for (int rg = 0; rg < 4; rg++) {
        float v = vr[rg];
        #pragma unroll
        for (int off = 8; off >= 1; off >>= 1) v += __shfl_xor(v, off, 16);
        if (l16 == 0)
            partials[(size_t)(rowBase + rg) * 16 + blockIdx.y] = v;
    }
}

// ---------------------------------------------------------------------------
extern "C" void kernel_launch(void* const* d_in, const int* in_sizes, int n_in,
                              void* d_out, int out_size, void* d_ws, size_t ws_size,
                              hipStream_t stream)
{
    const void* inc = d_in[0];
    const void* x   = d_in[1];
    const void* w   = d_in[2];
    const void* W1  = d_in[3];
    const void* b1  = d_in[4];
    const void* W2  = d_in[5];
    const void* b2  = d_in[6];
    const void* W3  = d_in[7];
    const void* b3  = d_in[8];

    char* p = (char*)d_ws;
    auto alloc = [&](size_t bytes) { void* r = p; p += (bytes + 255) & ~(size_t)255; return r; };
    int*    flagWS    = (int*)alloc(256);
    ushort* bs        = (ushort*)alloc((size_t)NROWS * NIN * 2);
    ushort* cbuf      = (ushort*)alloc((size_t)NROWS * NIN * 2);
    float*  partials  = (float*)alloc((size_t)MROWS * 16 * 4);
    ushort* h1WS      = (ushort*)alloc((size_t)MROWS * H1DIM * 2);
    ushort* h2WS      = (ushort*)alloc((size_t)MROWS * H2DIM * 2);
    ushort* W2T       = (ushort*)alloc((size_t)H2DIM * H1DIM * 2);
    ushort* W3T       = (ushort*)alloc((size_t)PIX * H2DIM * 2);
    ushort* W1c       = (ushort*)alloc((size_t)160 * H1DIM * 2);
    ushort* b1c       = (ushort*)alloc((size_t)H1DIM * 2);
    ushort* b2c       = (ushort*)alloc((size_t)H2DIM * 2);
    ushort* b3c       = (ushort*)alloc((size_t)PIX * 2);
    ushort* xc        = (ushort*)alloc((size_t)BATCH * PIX * 2);
    ushort* hatG      = (ushort*)alloc((size_t)NROWS * NIN * DOUT * 2);  // 47 MB, LAST
    bool haveHat = ((char*)hatG + (size_t)NROWS * NIN * DOUT * 2) <= ((char*)d_ws + ws_size);

    PrepArgs pa;
    pa.w = w;
    pa.src[0] = W1;  pa.dst[0] = W1c;  pa.n[0] = 160 * H1DIM;
    pa.src[1] = b1;  pa.dst[1] = b1c;  pa.n[1] = H1DIM;
    pa.src[2] = b2;  pa.dst[2] = b2c;  pa.n[2] = H2DIM;
    pa.src[3] = b3;  pa.dst[3] = b3c;  pa.n[3] = PIX;
    pa.src[4] = x;   pa.dst[4] = xc;   pa.n[4] = BATCH * PIX;
    pa.src[5] = W2;  pa.dst[5] = W2T;  pa.n[5] = 0;
    pa.src[6] = W3;  pa.dst[6] = W3T;  pa.n[6] = 0;
    pa.flag = flagWS;
    prep_kernel<<<dim3(800, 7), 256, 0, stream>>>(pa);

    if (haveHat) hat_build<<<dim3(9, 8, NOUTC), 256, 0, stream>>>(inc, w, hatG, flagWS);

    // iter 0: rc = 1; writes bscore->bs and fused layer-1 h1
    if (haveHat)
        reduce_pass<false><<<NROWS, 512, 0, stream>>>(
            hatG, inc, w, nullptr, nullptr, 1,
            W1c, b1c, h1WS, bs, nullptr, flagWS);
    else
        reduce_pass<true><<<NROWS, 512, 0, stream>>>(
            nullptr, inc, w, nullptr, nullptr, 1,
            W1c, b1c, h1WS, bs, nullptr, flagWS);

    for (int it = 0; it < 2; it++) {
        gemm2_kernel<<<dim3(18, 18), 256, 0, stream>>>(
            h1WS, W2T, b2c, h2WS, bs, cbuf);
        gemm3_kernel<<<dim3(18, NBY3), 256, 0, stream>>>(
            h2WS, W3T, b3c, xc, partials);

        int last = (it == 1);
        ushort* bsO = last ? nullptr : bs;
        ushort* h1o = last ? nullptr : h1WS;
        void*   fin = last ? d_out : nullptr;
        if (haveHat)
            reduce_pass<false><<<NROWS, 512, 0, stream>>>(
                hatG, inc, w, cbuf, partials, 0,
                W1c, b1c, h1o, bsO, fin, flagWS);
        else
            reduce_pass<true><<<NROWS, 512, 0, stream>>>(
                nullptr, inc, w, cbuf, partials, 0,
                W1c, b1c, h1o, bsO, fin, flagWS);
    }
}